// Round 7
// baseline (720.043 us; speedup 1.0000x reference)
//
#include <hip/hip_runtime.h>
#include <hip/hip_bf16.h>
#include <math.h>

#define SEQ   1024
#define TL    1024
#define DLOC  512
#define DTIM  32
#define DH    544       // 512+32
#define DUID  64
#define DF    608       // 544+64
#define NVOC  50000
#define NT_FINAL 391    // ceil(50000/128)
#define NPAD  50048     // 391*128

typedef __attribute__((ext_vector_type(8))) short short8;
typedef __attribute__((ext_vector_type(4))) float f32x4;
typedef __attribute__((ext_vector_type(4))) unsigned short u16x4;

#define WAITV8 asm volatile("s_waitcnt vmcnt(8)" ::: "memory")
#define WAITV4 asm volatile("s_waitcnt vmcnt(4)" ::: "memory")
#define WAITV0 asm volatile("s_waitcnt vmcnt(0)" ::: "memory")

__device__ __forceinline__ unsigned short f2bf(float f) {
    union { float f; unsigned int u; } x; x.f = f;
    unsigned int u = x.u;
    return (unsigned short)((u + 0x7fffu + ((u >> 16) & 1u)) >> 16);
}

// async global->LDS, 16B/lane; LDS dest = wave-uniform base + lane*16.
__device__ __forceinline__ void gll16(const unsigned short* g, unsigned short* l) {
    __builtin_amdgcn_global_load_lds(
        (const __attribute__((address_space(1))) void*)g,
        (__attribute__((address_space(3))) void*)l,
        16, 0, 0);
}

// ---------------------------------------------------------------------------
// Generic bf16 GEMM, 128x128 tile, 4 waves, depth-3 counted-vmcnt pipeline
// (4-buffer LDS ring, raw s_barrier, vmcnt(8/4/0) — never drain mid-loop).
// Bt[N'][K] with N' >= n0+128 allocated (zero/garbage-padded ok: cols guarded).
// EPI selects the fused epilogue.
// ---------------------------------------------------------------------------
enum { EPI_S = 0, EPI_PV = 1, EPI_G1 = 2, EPI_G2 = 3 };

template<int EPI>
__global__ __launch_bounds__(256) void gemm_p(
    const unsigned short* __restrict__ A,
    const unsigned short* __restrict__ Bt,
    int K, int N, int lda, int ldo,
    float* __restrict__ o1, unsigned short* __restrict__ o2,
    const float* __restrict__ p1, const float* __restrict__ p2,
    const float* __restrict__ p3, const float* __restrict__ p4)
{
    __shared__ __align__(16) unsigned short SMEM[32768]; // 64KB: As[4][4096]|Bs[4][4096]
    const int m0 = blockIdx.y << 7, n0 = blockIdx.x << 7;
    const int tid = threadIdx.x, w = tid >> 6, lane = tid & 63;
    const int wr = (w >> 1) << 6, wc = (w & 1) << 6;
    const int llo = lane & 15, lhi = lane >> 4;

    const int ch0 = (w * 2 + 0) * 64 + lane;
    const int ch1 = (w * 2 + 1) * 64 + lane;
    const int r0 = ch0 >> 2, s0 = (ch0 & 3) ^ ((r0 >> 1) & 3);
    const int r1 = ch1 >> 2, s1 = (ch1 & 3) ^ ((r1 >> 1) & 3);

    f32x4 acc[4][4];
    #pragma unroll
    for (int i = 0; i < 4; ++i)
        #pragma unroll
        for (int j = 0; j < 4; ++j)
            #pragma unroll
            for (int q = 0; q < 4; ++q) acc[i][j][q] = 0.0f;

    auto STAGE = [&](int buf, int kt) {
        const int k0 = kt << 5;
        unsigned short* As = &SMEM[buf * 4096];
        unsigned short* Bs = &SMEM[16384 + buf * 4096];
        gll16(&A [(size_t)(m0 + r0) * lda + k0 + s0 * 8], &As[(w * 2 + 0) * 512]);
        gll16(&A [(size_t)(m0 + r1) * lda + k0 + s1 * 8], &As[(w * 2 + 1) * 512]);
        gll16(&Bt[(size_t)(n0 + r0) * K   + k0 + s0 * 8], &Bs[(w * 2 + 0) * 512]);
        gll16(&Bt[(size_t)(n0 + r1) * K   + k0 + s1 * 8], &Bs[(w * 2 + 1) * 512]);
    };

    const int nk = K >> 5;   // >= 3 for all call sites
    STAGE(0, 0); STAGE(1, 1); STAGE(2, 2);
    WAITV8;                         // group 0 landed (12 outstanding -> <=8)
    __builtin_amdgcn_s_barrier();

    for (int t = 0; t < nk; ++t) {
        const unsigned short* As = &SMEM[(t & 3) * 4096];
        const unsigned short* Bs = &SMEM[16384 + (t & 3) * 4096];
        short8 af[4], bfv[4];
        #pragma unroll
        for (int fm = 0; fm < 4; ++fm) {
            int row = wr + fm * 16 + llo;
            af[fm] = *reinterpret_cast<const short8*>(&As[row * 32 + (lhi ^ ((row >> 1) & 3)) * 8]);
        }
        #pragma unroll
        for (int fn = 0; fn < 4; ++fn) {
            int row = wc + fn * 16 + llo;
            bfv[fn] = *reinterpret_cast<const short8*>(&Bs[row * 32 + (lhi ^ ((row >> 1) & 3)) * 8]);
        }
        if (t + 3 < nk) STAGE((t + 3) & 3, t + 3);
        __builtin_amdgcn_s_setprio(1);
        #pragma unroll
        for (int fm = 0; fm < 4; ++fm)
            #pragma unroll
            for (int fn = 0; fn < 4; ++fn)
                acc[fm][fn] = __builtin_amdgcn_mfma_f32_16x16x32_bf16(af[fm], bfv[fn], acc[fm][fn], 0, 0, 0);
        __builtin_amdgcn_s_setprio(0);
        if (t + 1 < nk) {
            if (t + 3 < nk)      WAITV8;   // oldest in-flight group (t+1) landed
            else if (t + 2 < nk) WAITV4;
            else                 WAITV0;
            __builtin_amdgcn_s_barrier();
        }
    }

    #pragma unroll
    for (int fm = 0; fm < 4; ++fm)
        #pragma unroll
        for (int fn = 0; fn < 4; ++fn)
            #pragma unroll
            for (int j = 0; j < 4; ++j) {
                int row = m0 + wr + fm * 16 + (lhi << 2) + j;
                int col = n0 + wc + fn * 16 + llo;
                float v = acc[fm][fn][j];
                if (EPI == EPI_S) {
                    if (col < N) o1[(size_t)row * ldo + col] = v;
                } else if (EPI == EPI_PV) {
                    if (col < N) {
                        o1[(size_t)row * ldo + col] = v;
                        o2[(size_t)row * ldo + col] = f2bf(v);
                    }
                } else if (EPI == EPI_G1) {
                    // cols<544: r-gate -> RHb ; cols 544..1087: z pre-act -> A01z
                    if (col < DH) {
                        float rg = 1.0f / (1.0f + __expf(-(v + p1[col])));
                        o2[(size_t)row * ldo + col] = f2bf(rg * p2[(size_t)row * DH + col]);
                    } else if (col < N) {
                        o1[(size_t)row * ldo + (col - DH)] = v;
                    }
                } else { // EPI_G2: out_state -> Ab
                    if (col < N) {
                        float z = 1.0f / (1.0f + __expf(-(p3[(size_t)row * DH + col] + p1[col])));
                        float g = tanhf(v + p2[col]);
                        float h = p4[(size_t)row * DH + col];
                        o2[(size_t)row * ldo + col] = f2bf(h + (1.0f - z) * (g - h));
                    }
                }
            }
}

// ---------------------------------------------------------------------------
// Final GEMM, two passes over the same tiles (same pipeline).
// PASS 1: sum(exp(y)) partials only (no Y write). PASS 2: Y = y - lse.
// ---------------------------------------------------------------------------
template<int PASS>
__global__ __launch_bounds__(256) void gemm_fin(
    const unsigned short* __restrict__ Ab,   // [1024][608]
    const unsigned short* __restrict__ Wt,   // [50048][608]
    const float* __restrict__ bias,
    float* __restrict__ Y,
    float* __restrict__ Psum,
    const float* __restrict__ LSE)
{
    __shared__ __align__(16) unsigned short SMEM[32768];
    const int bid = blockIdx.x;
    const int wid = (bid & 7) * NT_FINAL + (bid >> 3);   // bijective 8*391
    const int mt = wid & 7, nt = wid >> 3;
    const int m0 = mt << 7, n0 = nt << 7;

    const int tid = threadIdx.x, w = tid >> 6, lane = tid & 63;
    const int wr = (w >> 1) << 6, wc = (w & 1) << 6;
    const int llo = lane & 15, lhi = lane >> 4;

    const int ch0 = (w * 2 + 0) * 64 + lane;
    const int ch1 = (w * 2 + 1) * 64 + lane;
    const int r0 = ch0 >> 2, s0 = (ch0 & 3) ^ ((r0 >> 1) & 3);
    const int r1 = ch1 >> 2, s1 = (ch1 & 3) ^ ((r1 >> 1) & 3);

    f32x4 acc[4][4];
    #pragma unroll
    for (int i = 0; i < 4; ++i)
        #pragma unroll
        for (int j = 0; j < 4; ++j)
            #pragma unroll
            for (int q = 0; q < 4; ++q) acc[i][j][q] = 0.0f;

    auto STAGE = [&](int buf, int kt) {
        const int k0 = kt << 5;
        unsigned short* As = &SMEM[buf * 4096];
        unsigned short* Bs = &SMEM[16384 + buf * 4096];
        gll16(&Ab[(size_t)(m0 + r0) * DF + k0 + s0 * 8], &As[(w * 2 + 0) * 512]);
        gll16(&Ab[(size_t)(m0 + r1) * DF + k0 + s1 * 8], &As[(w * 2 + 1) * 512]);
        gll16(&Wt[(size_t)(n0 + r0) * DF + k0 + s0 * 8], &Bs[(w * 2 + 0) * 512]);
        gll16(&Wt[(size_t)(n0 + r1) * DF + k0 + s1 * 8], &Bs[(w * 2 + 1) * 512]);
    };

    const int nk = DF >> 5;   // 19
    STAGE(0, 0); STAGE(1, 1); STAGE(2, 2);
    WAITV8;
    __builtin_amdgcn_s_barrier();

    for (int t = 0; t < nk; ++t) {
        const unsigned short* As = &SMEM[(t & 3) * 4096];
        const unsigned short* Bs = &SMEM[16384 + (t & 3) * 4096];
        short8 af[4], bfv[4];
        #pragma unroll
        for (int fm = 0; fm < 4; ++fm) {
            int row = wr + fm * 16 + llo;
            af[fm] = *reinterpret_cast<const short8*>(&As[row * 32 + (lhi ^ ((row >> 1) & 3)) * 8]);
        }
        #pragma unroll
        for (int fn = 0; fn < 4; ++fn) {
            int row = wc + fn * 16 + llo;
            bfv[fn] = *reinterpret_cast<const short8*>(&Bs[row * 32 + (lhi ^ ((row >> 1) & 3)) * 8]);
        }
        if (t + 3 < nk) STAGE((t + 3) & 3, t + 3);
        __builtin_amdgcn_s_setprio(1);
        #pragma unroll
        for (int fm = 0; fm < 4; ++fm)
            #pragma unroll
            for (int fn = 0; fn < 4; ++fn)
                acc[fm][fn] = __builtin_amdgcn_mfma_f32_16x16x32_bf16(af[fm], bfv[fn], acc[fm][fn], 0, 0, 0);
        __builtin_amdgcn_s_setprio(0);
        if (t + 1 < nk) {
            if (t + 3 < nk)      WAITV8;
            else if (t + 2 < nk) WAITV4;
            else                 WAITV0;
            __builtin_amdgcn_s_barrier();
        }
    }

    if (PASS == 1) {
        // per-row partial sum(exp(y)) over this n-tile (no max: |y| small)
        __syncthreads();                       // LDS safe to alias
        float* red = (float*)SMEM;             // 128*33 floats
        #pragma unroll
        for (int fm = 0; fm < 4; ++fm)
            #pragma unroll
            for (int j = 0; j < 4; ++j) {
                int rowl = wr + fm * 16 + (lhi << 2) + j;
                float s = 0.0f;
                #pragma unroll
                for (int fn = 0; fn < 4; ++fn) {
                    int col = n0 + wc + fn * 16 + llo;
                    if (col < NVOC) s += __expf(acc[fm][fn][j] + bias[col]);
                }
                red[rowl * 33 + (wc >> 6) * 16 + llo] = s;
            }
        __syncthreads();
        if (tid < 128) {
            float t2 = 0.0f;
            #pragma unroll
            for (int i = 0; i < 32; ++i) t2 += red[tid * 33 + i];
            Psum[(size_t)(m0 + tid) * NT_FINAL + nt] = t2;
        }
    } else {
        // write log-softmax directly: y + bias - lse
        #pragma unroll
        for (int fm = 0; fm < 4; ++fm)
            #pragma unroll
            for (int j = 0; j < 4; ++j) {
                int rowl = wr + fm * 16 + (lhi << 2) + j;
                float l = LSE[m0 + rowl];
                #pragma unroll
                for (int fn = 0; fn < 4; ++fn) {
                    int col = n0 + wc + fn * 16 + llo;
                    if (col < NVOC)
                        Y[(size_t)(m0 + rowl) * NVOC + col] = acc[fm][fn][j] + bias[col] - l;
                }
            }
    }
}

__global__ __launch_bounds__(64) void k_combine(
    const float* __restrict__ Psum, float* __restrict__ LSE)
{
    int r = blockIdx.x, lane = threadIdx.x;
    float s = 0.0f;
    for (int i = lane; i < NT_FINAL; i += 64) s += Psum[(size_t)r * NT_FINAL + i];
    #pragma unroll
    for (int off = 32; off >= 1; off >>= 1) s += __shfl_xor(s, off);
    if (lane == 0) LSE[r] = logf(s);
}

// ---------------------------------------------------------------------------
// Converters
// ---------------------------------------------------------------------------
// W [608][50000] f32 -> Wt [50048][608] bf16 (transposed, zero-padded), vectorized
__global__ __launch_bounds__(256) void k_cvtW(
    const float* __restrict__ W, unsigned short* __restrict__ Wt)
{
    __shared__ unsigned short T[64][65];
    const int n0 = blockIdx.x * 64, k0 = blockIdx.y * 64;
    const int tid = threadIdx.x;
    #pragma unroll
    for (int i = 0; i < 4; ++i) {
        int idx = i * 256 + tid;           // 0..1023
        int kk = idx >> 4;                 // 0..63
        int nq = (idx & 15) << 2;          // 0,4,..,60
        int gk = k0 + kk, gn = n0 + nq;
        float4 v;
        if (gk < DF && gn < NVOC) v = *reinterpret_cast<const float4*>(&W[(size_t)gk * NVOC + gn]);
        else { v.x = v.y = v.z = v.w = 0.0f; }
        T[nq + 0][kk] = f2bf(v.x); T[nq + 1][kk] = f2bf(v.y);
        T[nq + 2][kk] = f2bf(v.z); T[nq + 3][kk] = f2bf(v.w);
    }
    __syncthreads();
    #pragma unroll
    for (int i = 0; i < 4; ++i) {
        int idx = i * 256 + tid;
        int nn = idx >> 4;                 // 0..63
        int kq = (idx & 15) << 2;          // 0..60
        int gk = k0 + kq;
        if (gk < DF) {
            u16x4 o; o[0] = T[nn][kq]; o[1] = T[nn][kq + 1]; o[2] = T[nn][kq + 2]; o[3] = T[nn][kq + 3];
            *reinterpret_cast<u16x4*>(&Wt[(size_t)(n0 + nn) * DF + gk]) = o;
        }
    }
}

// generic f32 [Kdim][srcLd] -> bf16 dst[n][k] transposed, rows beyond Nvalid = 0
__global__ __launch_bounds__(256) void k_cvtT(
    const float* __restrict__ src, unsigned short* __restrict__ dst,
    int Kdim, int Nvalid, int srcLd)
{
    __shared__ unsigned short T[64][65];
    const int n0 = blockIdx.x * 64, k0 = blockIdx.y * 64;
    const int tid = threadIdx.x;
    #pragma unroll
    for (int i = 0; i < 16; ++i) {
        int idx = i * 256 + tid;
        int kk = idx >> 6, nn = idx & 63;
        int gk = k0 + kk, gn = n0 + nn;
        float v = (gk < Kdim && gn < Nvalid) ? src[(size_t)gk * srcLd + gn] : 0.0f;
        T[nn][kk] = f2bf(v);
    }
    __syncthreads();
    #pragma unroll
    for (int i = 0; i < 16; ++i) {
        int idx = i * 256 + tid;
        int nn = idx >> 6, kk = idx & 63;
        int gk = k0 + kk;
        if (gk < Kdim) dst[(size_t)(n0 + nn) * Kdim + gk] = T[nn][kk];
    }
}

// bf16 src[Rdim][srcLd] -> bf16 dst[c][r], cols beyond Cvalid = 0
__global__ __launch_bounds__(256) void k_cvtT2(
    const unsigned short* __restrict__ src, unsigned short* __restrict__ dst,
    int Rdim, int Cvalid, int srcLd)
{
    __shared__ unsigned short T[64][65];
    const int c0 = blockIdx.x * 64, r0 = blockIdx.y * 64;
    const int tid = threadIdx.x;
    #pragma unroll
    for (int i = 0; i < 16; ++i) {
        int idx = i * 256 + tid;
        int rr = idx >> 6, cc = idx & 63;
        int gc = c0 + cc;
        T[cc][rr] = (gc < Cvalid) ? src[(size_t)(r0 + rr) * srcLd + gc] : (unsigned short)0;
    }
    __syncthreads();
    #pragma unroll
    for (int i = 0; i < 16; ++i) {
        int idx = i * 256 + tid;
        int cc = idx >> 6, rr = idx & 63;
        dst[(size_t)(c0 + cc) * Rdim + r0 + rr] = T[cc][rr];
    }
}

// ---------------------------------------------------------------------------
// Small kernels
// ---------------------------------------------------------------------------
__global__ __launch_bounds__(256) void k_build_x(
    const int* __restrict__ loc, const int* __restrict__ tim,
    const float* __restrict__ eloc, const float* __restrict__ etim,
    unsigned short* __restrict__ Xb)
{
    int r = blockIdx.x;
    int li = loc[r], ti = tim[r];
    for (int c = threadIdx.x; c < DH; c += 256) {
        float v = (c < DLOC) ? eloc[(size_t)li * DLOC + c]
                             : etim[(size_t)ti * DTIM + (c - DLOC)];
        Xb[(size_t)r * DH + c] = f2bf(v);
    }
}

__global__ __launch_bounds__(256) void k_softmax(
    const float* __restrict__ S, unsigned short* __restrict__ Pb)
{
    int r = blockIdx.x;
    const float* row = S + (size_t)r * SEQ;
    int tid = threadIdx.x;
    float v[4];
    float m = -INFINITY;
    #pragma unroll
    for (int i = 0; i < 4; ++i) { v[i] = row[tid + i * 256]; m = fmaxf(m, v[i]); }
    #pragma unroll
    for (int off = 32; off >= 1; off >>= 1) m = fmaxf(m, __shfl_xor(m, off));
    __shared__ float red[8];
    int w = tid >> 6;
    if ((tid & 63) == 0) red[w] = m;
    __syncthreads();
    m = fmaxf(fmaxf(red[0], red[1]), fmaxf(red[2], red[3]));
    float s = 0.0f;
    #pragma unroll
    for (int i = 0; i < 4; ++i) { v[i] = __expf(v[i] - m); s += v[i]; }
    #pragma unroll
    for (int off = 32; off >= 1; off >>= 1) s += __shfl_xor(s, off);
    __syncthreads();
    if ((tid & 63) == 0) red[4 + w] = s;
    __syncthreads();
    s = red[4] + red[5] + red[6] + red[7];
    float inv = 1.0f / s;
    #pragma unroll
    for (int i = 0; i < 4; ++i)
        Pb[(size_t)r * SEQ + tid + i * 256] = f2bf(v[i] * inv);
}

__global__ __launch_bounds__(256) void k_uid_b(
    const int* __restrict__ uid, const float* __restrict__ euid,
    unsigned short* __restrict__ Ab)
{
    int idx = blockIdx.x * 256 + threadIdx.x;
    if (idx >= TL * DUID) return;
    int r = idx >> 6, c = idx & 63;
    Ab[(size_t)r * DF + DH + c] = f2bf(euid[(size_t)uid[0] * DUID + c]);
}

// ---------------------------------------------------------------------------
extern "C" void kernel_launch(void* const* d_in, const int* in_sizes, int n_in,
                              void* d_out, int out_size, void* d_ws, size_t ws_size,
                              hipStream_t stream)
{
    const int*   loc  = (const int*)d_in[0];
    const int*   tim  = (const int*)d_in[1];
    const int*   uid  = (const int*)d_in[5];
    const float* eloc = (const float*)d_in[7];
    const float* etim = (const float*)d_in[8];
    const float* euid = (const float*)d_in[9];
    const float* gru_w = (const float*)d_in[10];
    const float* gru_b = (const float*)d_in[11];
    const float* fcw  = (const float*)d_in[12];
    const float* fcb  = (const float*)d_in[13];
    float* Y = (float*)d_out;

    const float* b0 = gru_b;
    const float* b1 = gru_b + DH;
    const float* b2 = gru_b + 2 * DH;

    // workspace layout (f32 first, then bf16; all sections 16B aligned)
    float* S    = (float*)d_ws;                    // 1024*1024
    float* Hf   = S    + (size_t)SEQ * SEQ;        // 1024*544
    float* A01z = Hf   + (size_t)TL * DH;          // 1024*544 (z pre-activations)
    float* Psum = A01z + (size_t)TL * DH;          // 1024*391
    float* LSE  = Psum + (size_t)TL * NT_FINAL;    // 1024
    unsigned short* Xb   = (unsigned short*)(LSE + 1024);  // 1024*544
    unsigned short* Xt   = Xb   + (size_t)TL * DH;         // 640*1024
    unsigned short* Pb   = Xt   + (size_t)640 * 1024;      // 1024*1024
    unsigned short* Hb   = Pb   + (size_t)SEQ * SEQ;       // 1024*544
    unsigned short* RHb  = Hb   + (size_t)TL * DH;         // 1024*544
    unsigned short* Ab   = RHb  + (size_t)TL * DH;         // 1024*608
    unsigned short* W01t = Ab   + (size_t)TL * DF;         // 1184*544
    unsigned short* W2t  = W01t + (size_t)1184 * DH;       // 640*544
    unsigned short* Wt   = W2t  + (size_t)640 * DH;        // 50048*608

    // --- weight conversions (input-only deps) ---
    k_cvtW<<<dim3(NPAD / 64, 10), 256, 0, stream>>>(fcw, Wt);
    k_cvtT<<<dim3(9, 9),  256, 0, stream>>>(gru_w,                     W01t,                   DH, DH, DH);
    k_cvtT<<<dim3(10, 9), 256, 0, stream>>>(gru_w + (size_t)DH * DH,   W01t + (size_t)DH * DH, DH, DH, DH);
    k_cvtT<<<dim3(10, 9), 256, 0, stream>>>(gru_w + 2*(size_t)DH * DH, W2t,                    DH, DH, DH);

    // --- x embed + transpose ---
    k_build_x<<<TL, 256, 0, stream>>>(loc, tim, eloc, etim, Xb);
    k_cvtT2<<<dim3(10, 16), 256, 0, stream>>>(Xb, Xt, TL, DH, DH);

    // --- attention ---
    gemm_p<EPI_S><<<dim3(8, 8), 256, 0, stream>>>(
        Xb, Xb, DH, SEQ, DH, SEQ, S, nullptr, nullptr, nullptr, nullptr, nullptr);
    k_softmax<<<SEQ, 256, 0, stream>>>(S, Pb);
    gemm_p<EPI_PV><<<dim3(5, 8), 256, 0, stream>>>(
        Pb, Xt, SEQ, DH, SEQ, DH, Hf, Hb, nullptr, nullptr, nullptr, nullptr);

    // --- GRU cell (gates fused into GEMM epilogues) ---
    gemm_p<EPI_G1><<<dim3(9, 8), 256, 0, stream>>>(
        Hb, W01t, DH, 1088, DH, DH, A01z, RHb, b0, Hf, nullptr, nullptr);
    gemm_p<EPI_G2><<<dim3(5, 8), 256, 0, stream>>>(
        RHb, W2t, DH, DH, DH, DF, nullptr, Ab, b1, b2, A01z, Hf);
    k_uid_b<<<(TL * DUID + 255) / 256, 256, 0, stream>>>(uid, euid, Ab);

    // --- final projection + log_softmax (two-pass, no k_sub) ---
    gemm_fin<1><<<8 * NT_FINAL, 256, 0, stream>>>(Ab, Wt, fcb, Y, Psum, nullptr);
    k_combine<<<TL, 64, 0, stream>>>(Psum, LSE);
    gemm_fin<2><<<8 * NT_FINAL, 256, 0, stream>>>(Ab, Wt, fcb, Y, Psum, LSE);
}